// Round 7
// baseline (280.464 us; speedup 1.0000x reference)
//
#include <hip/hip_runtime.h>
#include <hip/hip_bf16.h>

// CrossAttentionFusion: B=4, C=Cs=256, CI=128, H=W=64 -> N=M=4096
// R7:
//  - attn: BARRIER-FREE main loop. K double-buffered in VGPRs (prefetch one
//    tile ahead), V loaded at tile start (latency hidden behind QK chain).
//    No LDS/DMA in loop -> no vmcnt(0) barrier drains; waves decoupled.
//  - proj: outputs staged in LDS (frag-layout order) -> coalesced b128
//    global stores (kills the 2B-scatter that made proj ~70us).
//  - prep unchanged (x/z/W -> bf16 frag-order buffers).
//
// qk-frag (Q B-op / K A-op), per 32-row group g:
//   addr = g*4096 + (ch>>4)*512 + ((ch>>3)&1)*256 + row*8 + (ch&7)
//   (K rows permuted: row = perm(key&31), perm = l32^12 if (l32>>2)&3 in {1,2})
// V-frag (PV A-op), per 32-key group g: addr = g*8192 + (ch>>5)*1024
//   + ((key>>4)&1)*512 + ((key>>3)&1)*256 + (ch&31)*8 + (key&7)
// X-frag / W-frag as R6.

typedef __bf16  bf16x8  __attribute__((ext_vector_type(8)));
typedef float   f32x16  __attribute__((ext_vector_type(16)));

#define LOG2E 1.4426950408889634f

union BF8 { __hip_bfloat162 h[4]; bf16x8 v; };
union U4  { unsigned u[4]; bf16x8 v; };

__device__ inline bf16x8 pack8(const float f[8]) {
  BF8 u;
#pragma unroll
  for (int i = 0; i < 4; i++)
    u.h[i] = __float22bfloat162_rn(float2{f[2 * i], f[2 * i + 1]});
  return u.v;
}

// ---------------------------------------------------------------------------
// prep: blocks [0,512): x/z -> X-frag bf16 (LDS transpose);
//       blocks [512,516): W -> W-frag bf16.  (unchanged from R6)
// ---------------------------------------------------------------------------
__global__ __launch_bounds__(256) void prep_kernel(
    const float* __restrict__ x, const float* __restrict__ z,
    const float* __restrict__ Wq, const float* __restrict__ Wk,
    const float* __restrict__ Wv,
    __hip_bfloat16* __restrict__ xf, __hip_bfloat16* __restrict__ zf,
    __hip_bfloat16* __restrict__ wfr)
{
  __shared__ float lds[256 * 65];
  const int bi = blockIdx.x;
  const int tid = threadIdx.x;
  if (bi < 512) {
    const int sel = bi >> 8;
    const int b   = (bi >> 6) & 3;
    const int pc  = bi & 63;
    const float* in = sel ? z : x;
    __hip_bfloat16* outp = sel ? zf : xf;
    const size_t ib = (size_t)b * 256 * 4096 + pc * 64;
#pragma unroll 4
    for (int r = 0; r < 64; r++) {
      int ch = r * 4 + (tid >> 6);
      lds[ch * 65 + (tid & 63)] = in[ib + (size_t)ch * 4096 + (tid & 63)];
    }
    __syncthreads();
    const size_t ob = ((size_t)(b * 128 + pc * 2)) * 8192;
#pragma unroll
    for (int i = 0; i < 8; i++) {
      int c = i * 256 + tid;
      int grp = c >> 10, cs = (c >> 6) & 15, rem = c & 63;
      int hf = rem >> 5, l32 = rem & 31;
      float f[8];
      int chb = cs * 16 + hf * 8;
#pragma unroll
      for (int j = 0; j < 8; j++)
        f[j] = lds[(chb + j) * 65 + grp * 32 + l32];
      *(bf16x8*)(outp + ob + grp * 8192 + cs * 512 + hf * 256 + l32 * 8) =
          pack8(f);
    }
  } else {
    const int base = (bi - 512) * 4096;
#pragma unroll
    for (int i = 0; i < 16; i++) {
      int c = base + i * 256 + tid;
      const float* Ws; __hip_bfloat16* dst; int rc;
      if (c < 4096)      { Ws = Wq; dst = wfr;          rc = c; }
      else if (c < 8192) { Ws = Wk; dst = wfr + 32768;  rc = c - 4096; }
      else               { Ws = Wv; dst = wfr + 65536;  rc = c - 8192; }
      int ot = rc >> 10, cs = (rc >> 6) & 15, rem = rc & 63;
      int hf = rem >> 5, l32 = rem & 31;
      const float* src = Ws + (ot * 32 + l32) * 256 + cs * 16 + hf * 8;
      float f[8];
#pragma unroll
      for (int j = 0; j < 8; j++) f[j] = src[j];
      *(bf16x8*)(dst + ot * 8192 + cs * 512 + hf * 256 + l32 * 8) = pack8(f);
    }
  }
}

// ---------------------------------------------------------------------------
// proj: MFMA GEMM, outputs staged in LDS -> coalesced b128 stores.
// Grid 512: [0,128) q, [128,256) k, [256,512) v.
// Block: (b, 128-pixel chunk); wave = 32-och tile; 4 iters of 32 pixels.
// ---------------------------------------------------------------------------
__global__ __launch_bounds__(256, 2) void proj_mfma(
    const __hip_bfloat16* __restrict__ xf, const __hip_bfloat16* __restrict__ zf,
    const __hip_bfloat16* __restrict__ wfr,
    const float* __restrict__ bq, const float* __restrict__ bk,
    const float* __restrict__ bv,
    __hip_bfloat16* __restrict__ qp, __hip_bfloat16* __restrict__ kp,
    __hip_bfloat16* __restrict__ vp)
{
  __shared__ __hip_bfloat16 st[4][4096];   // 32 KiB staging, frag-layout order
  const int bi = blockIdx.x;
  int mode, b, pc, h = 0;
  if (bi < 256) { mode = bi >> 7; b = (bi >> 5) & 3; pc = bi & 31; }
  else { int j = bi - 256; mode = 2; b = j >> 6; pc = (j >> 1) & 31; h = j & 1; }
  const int tid = threadIdx.x, w = tid >> 6, lane = tid & 63,
            l32 = lane & 31, half = lane >> 5;

  const __hip_bfloat16* X = (mode == 0) ? xf : zf;
  const int wtile = (mode == 2 ? h * 4 : 0) + w;
  const int wbase = (mode == 0) ? 0 : (mode == 1) ? 32768 : 65536;
  const __hip_bfloat16* wp = wfr + wbase + wtile * 8192 + lane * 8;
  bf16x8 wfg[16];
#pragma unroll
  for (int cs = 0; cs < 16; cs++) wfg[cs] = *(const bf16x8*)(wp + cs * 512);

  const float* bias = (mode == 0) ? bq : (mode == 1) ? bk : bv;
  const int ochb = (mode == 2 ? h * 128 : 0) + w * 32;
  float bb[16];
#pragma unroll
  for (int r = 0; r < 16; r++)
    bb[r] = bias[ochb + (r & 3) + 8 * (r >> 2) + 4 * half];

  // key-row permutation (shuffle-free PV in attn)
  const int t4 = (l32 >> 2) & 3;
  const int kperm = (t4 == 1 || t4 == 2) ? (l32 ^ 12) : l32;

#pragma unroll 1
  for (int it = 0; it < 4; it++) {
    const int pg = pc * 4 + it;
    const __hip_bfloat16* xb = X + ((size_t)(b * 128 + pg)) * 8192 + lane * 8;
    f32x16 O = {};
#pragma unroll
    for (int cs = 0; cs < 16; cs++) {
      bf16x8 xr = *(const bf16x8*)(xb + cs * 512);
      O = __builtin_amdgcn_mfma_f32_32x32x16_bf16(wfg[cs], xr, O, 0, 0, 0);
    }
    if (mode != 2) {
#pragma unroll
      for (int r = 0; r < 16; r++) {
        int oc = w * 32 + (r & 3) + 8 * (r >> 2) + 4 * half;
        float val = O[r] + bb[r];
        if (mode == 0) val *= LOG2E;
        int row = (mode == 1) ? kperm : l32;
        st[it][(oc >> 4) * 512 + ((oc >> 3) & 1) * 256 + row * 8 + (oc & 7)] =
            __float2bfloat16(val);
      }
    } else {
#pragma unroll
      for (int r = 0; r < 16; r++) {
        int ocr = w * 32 + (r & 3) + 8 * (r >> 2) + 4 * half;  // within 128-half
        st[it][(ocr >> 5) * 1024 + ((l32 >> 4) & 1) * 512 +
               ((l32 >> 3) & 1) * 256 + (ocr & 31) * 8 + (l32 & 7)] =
            __float2bfloat16(O[r] + bb[r]);
      }
    }
  }
  __syncthreads();

  // coalesced writeout: 2048 b128 chunks, 8 per thread
  if (mode != 2) {
    __hip_bfloat16* dst = (mode == 0 ? qp : kp)
                        + ((size_t)(b * 128 + pc * 4)) * 4096;
#pragma unroll
    for (int i = 0; i < 8; i++) {
      int c = i * 256 + tid;             // [0,2048): grp = c>>9, rem = c&511
      *(bf16x8*)(dst + (size_t)c * 8) = *(const bf16x8*)&st[c >> 9][(c & 511) * 8];
    }
  } else {
#pragma unroll
    for (int i = 0; i < 8; i++) {
      int c = i * 256 + tid;
      int grp = c >> 9, rem = c & 511;
      __hip_bfloat16* dst = vp + ((size_t)(b * 128 + pc * 4 + grp)) * 8192
                          + h * 4096 + (size_t)rem * 8;
      *(bf16x8*)dst = *(const bf16x8*)&st[grp][rem * 8];
    }
  }
}

// ---------------------------------------------------------------------------
// attn: barrier-free flash attention, all operands direct from global frags.
// Block (b, 32 q), 4 waves = (kh, chh). Per wave: 64 tiles of 32 keys
// (kh half = 2048 keys). K dbuf prefetch in VGPRs; V issued at tile start.
// ---------------------------------------------------------------------------
struct AttnSmem {
  float ostage[256][33];          // epilogue [ch][q], pad 33
  float redu[4][32];
  float rinv[32];
};

__global__ __launch_bounds__(256, 2) void attn_kernel(
    const __hip_bfloat16* __restrict__ qv, const __hip_bfloat16* __restrict__ kv,
    const __hip_bfloat16* __restrict__ vv,
    const float* __restrict__ x_main, const float* __restrict__ gammap,
    float* __restrict__ out)
{
  __shared__ AttnSmem sm;
  const int i  = blockIdx.x;           // 512 blocks
  const int b  = (i & 7) >> 1;         // XCD-pair -> batch (K+V L2-resident)
  const int qt = ((i >> 3) << 1) | (i & 1);
  const int n0 = qt * 32;
  const int tid  = threadIdx.x;
  const int w    = tid >> 6, lane = tid & 63, l32 = lane & 31;
  const int kh   = w >> 1, chh = w & 1;

  // Q B-fragments (coalesced frag-order)
  bf16x8 qf[8];
  {
    const __hip_bfloat16* qb = qv + ((size_t)(b * 128 + qt)) * 4096 + lane * 8;
#pragma unroll
    for (int cs = 0; cs < 8; cs++) qf[cs] = *(const bf16x8*)(qb + cs * 512);
  }

  // per-wave stream bases: tile t -> group t*2+kh
  const __hip_bfloat16* kgh = kv + (size_t)(b * 128 + kh) * 4096 + lane * 8;
  const __hip_bfloat16* vgh = vv + (size_t)(b * 128 + kh) * 8192
                            + chh * 4096 + lane * 8;

  f32x16 Oacc[4];   // O^T: 128 ch (chh half) x 32 q, partial over kh keys
#pragma unroll
  for (int c = 0; c < 4; c++)
#pragma unroll
    for (int r = 0; r < 16; r++) Oacc[c][r] = 0.f;

  float l_lane = 0.f;

  bf16x8 KA[8], KB[8];
#pragma unroll
  for (int cs = 0; cs < 8; cs++) KA[cs] = *(const bf16x8*)(kgh + cs * 512);

  auto body = [&](int t, bf16x8* Kc, bf16x8* Kn) {
    // V for tile t: issue FIRST so latency hides behind QK chain
    const __hip_bfloat16* vb = vgh + (size_t)t * 16384;
    bf16x8 Vc[8];
#pragma unroll
    for (int c = 0; c < 4; c++) {
      Vc[2 * c]     = *(const bf16x8*)(vb + c * 1024);
      Vc[2 * c + 1] = *(const bf16x8*)(vb + c * 1024 + 512);
    }
    // prefetch K for tile t+1 (clamped; avoids divergent branch)
    {
      int tn = (t < 63) ? (t + 1) : 63;
      const __hip_bfloat16* kb = kgh + (size_t)tn * 8192;
#pragma unroll
      for (int cs = 0; cs < 8; cs++) Kn[cs] = *(const bf16x8*)(kb + cs * 512);
    }
    // S^T = K Q (8-MFMA chain on prefetched Kc)
    f32x16 S = {};
#pragma unroll
    for (int cs = 0; cs < 8; cs++)
      S = __builtin_amdgcn_mfma_f32_32x32x16_bf16(Kc[cs], qf[cs], S, 0, 0, 0);
    // P = exp2(S - 64); permuted-K means p2[0..3]/p2[4..7] ARE PV B-frags
    unsigned p2[8];
    float lsub = 0.f;
#pragma unroll
    for (int i2 = 0; i2 < 8; i2++) {
      float a = exp2f(S[2 * i2]     - 64.0f);
      float c = exp2f(S[2 * i2 + 1] - 64.0f);
      lsub += a + c;
      union { __hip_bfloat162 h; unsigned u; } cv;
      cv.h = __float22bfloat162_rn(float2{a, c});
      p2[i2] = cv.u;
    }
    l_lane += lsub;
    U4 f0, f1;
    f0.u[0] = p2[0]; f0.u[1] = p2[1]; f0.u[2] = p2[2]; f0.u[3] = p2[3];
    f1.u[0] = p2[4]; f1.u[1] = p2[5]; f1.u[2] = p2[6]; f1.u[3] = p2[7];
    const bf16x8 pf0 = f0.v, pf1 = f1.v;
#pragma unroll
    for (int c = 0; c < 4; c++) {
      Oacc[c] = __builtin_amdgcn_mfma_f32_32x32x16_bf16(Vc[2 * c],     pf0, Oacc[c], 0, 0, 0);
      Oacc[c] = __builtin_amdgcn_mfma_f32_32x32x16_bf16(Vc[2 * c + 1], pf1, Oacc[c], 0, 0, 0);
    }
  };

  // ---- barrier-free main loop (unrolled x2 for K reg double-buffer) ----
#pragma unroll 1
  for (int t = 0; t < 64; t += 2) {
    body(t,     KA, KB);
    body(t + 1, KB, KA);
  }

  // ---- epilogue: publish l, kh-merge via ostage (ch rows), writeout ----
  float lfull = l_lane + __shfl_xor(l_lane, 32);
  if (lane < 32) sm.redu[w][l32] = lfull;
  __syncthreads();
  const int hb = lane >> 5;
  if (kh == 0) {
#pragma unroll
    for (int c = 0; c < 4; c++) {
#pragma unroll
      for (int r = 0; r < 16; r++) {
        int ch = (chh * 4 + c) * 32 + (r & 3) + 8 * (r >> 2) + 4 * hb;
        sm.ostage[ch][l32] = Oacc[c][r];
      }
    }
  }
  if (tid < 32) sm.rinv[tid] = 1.0f / (sm.redu[0][tid] + sm.redu[2][tid]);
  __syncthreads();
  if (kh == 1) {
#pragma unroll
    for (int c = 0; c < 4; c++) {
#pragma unroll
      for (int r = 0; r < 16; r++) {
        int ch = (chh * 4 + c) * 32 + (r & 3) + 8 * (r >> 2) + 4 * hb;
        sm.ostage[ch][l32] += Oacc[c][r];
      }
    }
  }
  __syncthreads();

  const float gmm = gammap[0];
  const int pix = tid & 31;
  const float ri = sm.rinv[pix];
#pragma unroll
  for (int j = 0; j < 32; ++j) {
    int ch = (tid >> 5) * 32 + j;
    size_t g = ((size_t)(b * 256 + ch)) * 4096 + n0 + pix;
    out[g] = gmm * sm.ostage[ch][pix] * ri + x_main[g];
  }
}

// ---------------------------------------------------------------------------
extern "C" void kernel_launch(void* const* d_in, const int* in_sizes, int n_in,
                              void* d_out, int out_size, void* d_ws, size_t ws_size,
                              hipStream_t stream) {
  (void)in_sizes; (void)n_in; (void)out_size; (void)ws_size;
  const float* x  = (const float*)d_in[0];
  const float* z  = (const float*)d_in[1];
  const float* Wq = (const float*)d_in[2];
  const float* bq = (const float*)d_in[3];
  const float* Wk = (const float*)d_in[4];
  const float* bk = (const float*)d_in[5];
  const float* Wv = (const float*)d_in[6];
  const float* bv = (const float*)d_in[7];
  const float* gm = (const float*)d_in[8];
  float* out = (float*)d_out;

  char* ws = (char*)d_ws;
  const size_t MB = 1024 * 1024;
  __hip_bfloat16* qp  = (__hip_bfloat16*)(ws);             // 4 MiB
  __hip_bfloat16* kp  = (__hip_bfloat16*)(ws + 4 * MB);    // 4 MiB
  __hip_bfloat16* vp  = (__hip_bfloat16*)(ws + 8 * MB);    // 8 MiB
  __hip_bfloat16* xfp = (__hip_bfloat16*)(ws + 16 * MB);   // 8 MiB
  __hip_bfloat16* zfp = (__hip_bfloat16*)(ws + 24 * MB);   // 8 MiB
  __hip_bfloat16* wfp = (__hip_bfloat16*)(ws + 32 * MB);   // 256 KiB

  prep_kernel<<<516, 256, 0, stream>>>(x, z, Wq, Wk, Wv, xfp, zfp, wfp);
  proj_mfma  <<<512, 256, 0, stream>>>(xfp, zfp, wfp, bq, bk, bv, qp, kp, vp);
  attn_kernel<<<512, 256, 0, stream>>>(qp, kp, vp, x, gm, out);
}

// Round 8
// 209.788 us; speedup vs baseline: 1.3369x; 1.3369x over previous
//
#include <hip/hip_runtime.h>
#include <hip/hip_bf16.h>

// CrossAttentionFusion: B=4, C=Cs=256, CI=128, H=W=64 -> N=M=4096
// R8 = R6 structure (best: 117us attn) + tile-order stagger:
//  - attn: per-block start tile t0 = qt & 63 (softmax uses fixed anchor ->
//    tile order permutable). Kills the XCD-wide lockstep L2 hotspot where
//    all 64 blocks/XCD read the same 48KB K/V region simultaneously.
//    V loads hoisted to tile start (latency hides behind LDS-K QK chain).
//    K via DMA+LDS dbuf (cross-wave dedup), 1 barrier/tile.
//  - proj: R6 direct-store version (scatter stores are fire-and-forget;
//    R7's LDS staging was -13us) + 2-pixel-group MFMA interleave (ILP 2).
//  - prep: float4-vectorized x/z loads (was 64 scalar b32/thread).
//
// qk-frag (Q B-op / K A-op), per 32-row group g:
//   addr = g*4096 + (ch>>4)*512 + ((ch>>3)&1)*256 + row*8 + (ch&7)
//   (K rows permuted: row = l32^12 if (l32>>2)&3 in {1,2} -> shuffle-free PV)
// V-frag (PV A-op), per 32-key group g: addr = g*8192 + (ch>>5)*1024
//   + ((key>>4)&1)*512 + ((key>>3)&1)*256 + (ch&31)*8 + (key&7)

typedef __bf16  bf16x8  __attribute__((ext_vector_type(8)));
typedef float   f32x16  __attribute__((ext_vector_type(16)));

#define LOG2E 1.4426950408889634f

union BF8 { __hip_bfloat162 h[4]; bf16x8 v; };
union U4  { unsigned u[4]; bf16x8 v; };

__device__ inline bf16x8 pack8(const float f[8]) {
  BF8 u;
#pragma unroll
  for (int i = 0; i < 4; i++)
    u.h[i] = __float22bfloat162_rn(float2{f[2 * i], f[2 * i + 1]});
  return u.v;
}

__device__ inline void dma16(const void* g, void* l) {
  __builtin_amdgcn_global_load_lds(
      (const __attribute__((address_space(1))) unsigned int*)g,
      (__attribute__((address_space(3))) unsigned int*)l, 16, 0, 0);
}

// ---------------------------------------------------------------------------
// prep: blocks [0,512): x/z -> X-frag bf16 (LDS transpose, float4 loads);
//       blocks [512,516): W -> W-frag bf16.
// ---------------------------------------------------------------------------
__global__ __launch_bounds__(256) void prep_kernel(
    const float* __restrict__ x, const float* __restrict__ z,
    const float* __restrict__ Wq, const float* __restrict__ Wk,
    const float* __restrict__ Wv,
    __hip_bfloat16* __restrict__ xf, __hip_bfloat16* __restrict__ zf,
    __hip_bfloat16* __restrict__ wfr)
{
  __shared__ float lds[256 * 68];   // pitch 68: 16B-aligned rows, conflict-free
  const int bi = blockIdx.x;
  const int tid = threadIdx.x;
  if (bi < 512) {
    const int sel = bi >> 8;
    const int b   = (bi >> 6) & 3;
    const int pc  = bi & 63;
    const float* in = sel ? z : x;
    __hip_bfloat16* outp = sel ? zf : xf;
    const size_t ib = (size_t)b * 256 * 4096 + pc * 64;
    const int pix4 = (tid & 15) * 4;
#pragma unroll
    for (int it = 0; it < 16; it++) {
      int ch = it * 16 + (tid >> 4);
      float4 v4 = *(const float4*)&in[ib + (size_t)ch * 4096 + pix4];
      *(float4*)&lds[ch * 68 + pix4] = v4;
    }
    __syncthreads();
    const size_t ob = ((size_t)(b * 128 + pc * 2)) * 8192;
#pragma unroll
    for (int i = 0; i < 8; i++) {
      int c = i * 256 + tid;
      int grp = c >> 10, cs = (c >> 6) & 15, rem = c & 63;
      int hf = rem >> 5, l32 = rem & 31;
      float f[8];
      int chb = cs * 16 + hf * 8;
#pragma unroll
      for (int j = 0; j < 8; j++)
        f[j] = lds[(chb + j) * 68 + grp * 32 + l32];
      *(bf16x8*)(outp + ob + grp * 8192 + cs * 512 + hf * 256 + l32 * 8) =
          pack8(f);
    }
  } else {
    const int base = (bi - 512) * 4096;
#pragma unroll
    for (int i = 0; i < 16; i++) {
      int c = base + i * 256 + tid;
      const float* Ws; __hip_bfloat16* dst; int rc;
      if (c < 4096)      { Ws = Wq; dst = wfr;          rc = c; }
      else if (c < 8192) { Ws = Wk; dst = wfr + 32768;  rc = c - 4096; }
      else               { Ws = Wv; dst = wfr + 65536;  rc = c - 8192; }
      int ot = rc >> 10, cs = (rc >> 6) & 15, rem = rc & 63;
      int hf = rem >> 5, l32 = rem & 31;
      const float* src = Ws + (ot * 32 + l32) * 256 + cs * 16 + hf * 8;
      float f[8];
#pragma unroll
      for (int j = 0; j < 8; j++) f[j] = src[j];
      *(bf16x8*)(dst + ot * 8192 + cs * 512 + hf * 256 + l32 * 8) = pack8(f);
    }
  }
}

// ---------------------------------------------------------------------------
// proj: LDS-free MFMA GEMM, 2-pixel-group interleave (ILP 2), direct stores.
// Grid 512: [0,128) q, [128,256) k, [256,512) v.
// ---------------------------------------------------------------------------
__global__ __launch_bounds__(256, 2) void proj_mfma(
    const __hip_bfloat16* __restrict__ xf, const __hip_bfloat16* __restrict__ zf,
    const __hip_bfloat16* __restrict__ wfr,
    const float* __restrict__ bq, const float* __restrict__ bk,
    const float* __restrict__ bv,
    __hip_bfloat16* __restrict__ qp, __hip_bfloat16* __restrict__ kp,
    __hip_bfloat16* __restrict__ vp)
{
  const int bi = blockIdx.x;
  int mode, b, pc, h = 0;
  if (bi < 256) { mode = bi >> 7; b = (bi >> 5) & 3; pc = bi & 31; }
  else { int j = bi - 256; mode = 2; b = j >> 6; pc = (j >> 1) & 31; h = j & 1; }
  const int tid = threadIdx.x, w = tid >> 6, lane = tid & 63,
            l32 = lane & 31, half = lane >> 5;

  const __hip_bfloat16* X = (mode == 0) ? xf : zf;
  const int wtile = (mode == 2 ? h * 4 : 0) + w;
  const int wbase = (mode == 0) ? 0 : (mode == 1) ? 32768 : 65536;
  const __hip_bfloat16* wp = wfr + wbase + wtile * 8192 + lane * 8;
  bf16x8 wfg[16];
#pragma unroll
  for (int cs = 0; cs < 16; cs++) wfg[cs] = *(const bf16x8*)(wp + cs * 512);

  const float* bias = (mode == 0) ? bq : (mode == 1) ? bk : bv;
  const int ochb = (mode == 2 ? h * 128 : 0) + w * 32;
  float bb[16];
#pragma unroll
  for (int r = 0; r < 16; r++)
    bb[r] = bias[ochb + (r & 3) + 8 * (r >> 2) + 4 * half];

  const int t4 = (l32 >> 2) & 3;
  const int kperm = (t4 == 1 || t4 == 2) ? (l32 ^ 12) : l32;

#pragma unroll 1
  for (int itp = 0; itp < 2; itp++) {
    const int pg0 = pc * 4 + itp * 2;
    const __hip_bfloat16* xb0 = X + ((size_t)(b * 128 + pg0)) * 8192 + lane * 8;
    const __hip_bfloat16* xb1 = xb0 + 8192;
    f32x16 O0 = {}, O1 = {};
#pragma unroll
    for (int cs = 0; cs < 16; cs++) {
      bf16x8 xr0 = *(const bf16x8*)(xb0 + cs * 512);
      bf16x8 xr1 = *(const bf16x8*)(xb1 + cs * 512);
      O0 = __builtin_amdgcn_mfma_f32_32x32x16_bf16(wfg[cs], xr0, O0, 0, 0, 0);
      O1 = __builtin_amdgcn_mfma_f32_32x32x16_bf16(wfg[cs], xr1, O1, 0, 0, 0);
    }
#pragma unroll
    for (int p = 0; p < 2; p++) {
      const f32x16& O = p ? O1 : O0;
      const int pg = pg0 + p;
      if (mode == 0) {
        __hip_bfloat16* qb = qp + ((size_t)(b * 128 + pg)) * 4096;
#pragma unroll
        for (int r = 0; r < 16; r++) {
          int oc = ochb + (r & 3) + 8 * (r >> 2) + 4 * half;
          qb[(oc >> 4) * 512 + ((oc >> 3) & 1) * 256 + l32 * 8 + (oc & 7)] =
              __float2bfloat16((O[r] + bb[r]) * LOG2E);
        }
      } else if (mode == 1) {
        __hip_bfloat16* kb = kp + ((size_t)(b * 128 + pg)) * 4096;
#pragma unroll
        for (int r = 0; r < 16; r++) {
          int oc = ochb + (r & 3) + 8 * (r >> 2) + 4 * half;
          kb[(oc >> 4) * 512 + ((oc >> 3) & 1) * 256 + kperm * 8 + (oc & 7)] =
              __float2bfloat16(O[r] + bb[r]);
        }
      } else {
        __hip_bfloat16* vb = vp + ((size_t)(b * 128 + pg)) * 8192
            + (h * 4 + w) * 1024 + (l32 >> 4) * 512 + ((l32 >> 3) & 1) * 256
            + (l32 & 7);
#pragma unroll
        for (int r = 0; r < 16; r++) {
          int rr = (r & 3) + 8 * (r >> 2) + 4 * half;
          vb[rr * 8] = __float2bfloat16(O[r] + bb[r]);
        }
      }
    }
  }
}

// ---------------------------------------------------------------------------
// attn: R6 structure + tile stagger + V-early. Block (b, 32 q), 4 waves =
// (kh, chh). K DMA+LDS dbuf; V direct global frag loads; 64 tiles staggered.
// ---------------------------------------------------------------------------
struct AttnSmem {
  union {
    __hip_bfloat16 kbuf[2][8192];   // 2 x 16 KiB
    float ostage[256][33];          // epilogue [ch][q], pad 33
  } u;
  float redu[4][32];
  float rinv[32];
};

__global__ __launch_bounds__(256, 3) void attn_kernel(
    const __hip_bfloat16* __restrict__ qv, const __hip_bfloat16* __restrict__ kv,
    const __hip_bfloat16* __restrict__ vv,
    const float* __restrict__ x_main, const float* __restrict__ gammap,
    float* __restrict__ out)
{
  __shared__ AttnSmem sm;
  const int i  = blockIdx.x;           // 512 blocks
  const int b  = (i & 7) >> 1;         // XCD-pair -> batch (K+V L2-resident)
  const int qt = ((i >> 3) << 1) | (i & 1);
  const int n0 = qt * 32;
  const int tid  = threadIdx.x;
  const int w    = tid >> 6, lane = tid & 63, l32 = lane & 31;
  const int kh   = w >> 1, chh = w & 1;
  const int t0   = qt & 63;            // stagger: de-correlate block streams

  // Q B-fragments (coalesced frag-order)
  bf16x8 qf[8];
  {
    const __hip_bfloat16* qb = qv + ((size_t)(b * 128 + qt)) * 4096 + lane * 8;
#pragma unroll
    for (int cs = 0; cs < 8; cs++) qf[cs] = *(const bf16x8*)(qb + cs * 512);
  }

  const __hip_bfloat16* kg = kv + (size_t)(b * 128) * 4096;
  const __hip_bfloat16* vg = vv + (size_t)(b * 128) * 8192;

  auto stage = [&](int ta, int par) {
    __hip_bfloat16* kd = sm.u.kbuf[par];
    const __hip_bfloat16* ksrc = kg + (size_t)ta * 8192 + lane * 8;
#pragma unroll
    for (int c = 0; c < 4; c++) {
      int ck = w * 4 + c;
      dma16(ksrc + ck * 512, kd + ck * 512 + lane * 8);
    }
  };

  f32x16 Oacc[4];   // O^T: 128 ch (chh half) x 32 q, partial over kh keys
#pragma unroll
  for (int c = 0; c < 4; c++)
#pragma unroll
    for (int r = 0; r < 16; r++) Oacc[c][r] = 0.f;

  float l_lane = 0.f;

  // one tile: V loads first (latency hides behind QK LDS chain), then
  // S^T = K Q, P = exp2(S-64) (shuffle-free via K perm), PV.
  auto body = [&](int par, int ta) {
    const __hip_bfloat16* vb = vg + (size_t)(ta * 2 + kh) * 8192
                             + chh * 4096 + lane * 8;
    bf16x8 Vc[8];
#pragma unroll
    for (int c = 0; c < 4; c++) {
      Vc[2 * c]     = *(const bf16x8*)(vb + c * 1024);
      Vc[2 * c + 1] = *(const bf16x8*)(vb + c * 1024 + 512);
    }
    const __hip_bfloat16* kbase = sm.u.kbuf[par] + kh * 4096 + lane * 8;
    f32x16 S = {};
#pragma unroll
    for (int cs = 0; cs < 8; cs++) {
      bf16x8 kf = *(const bf16x8*)(kbase + cs * 512);
      S = __builtin_amdgcn_mfma_f32_32x32x16_bf16(kf, qf[cs], S, 0, 0, 0);
    }
    unsigned p2[8];
    float lsub = 0.f;
#pragma unroll
    for (int i2 = 0; i2 < 8; i2++) {
      float a = exp2f(S[2 * i2]     - 64.0f);
      float c = exp2f(S[2 * i2 + 1] - 64.0f);
      lsub += a + c;
      union { __hip_bfloat162 h; unsigned u; } cv;
      cv.h = __float22bfloat162_rn(float2{a, c});
      p2[i2] = cv.u;
    }
    l_lane += lsub;
    U4 f0, f1;
    f0.u[0] = p2[0]; f0.u[1] = p2[1]; f0.u[2] = p2[2]; f0.u[3] = p2[3];
    f1.u[0] = p2[4]; f1.u[1] = p2[5]; f1.u[2] = p2[6]; f1.u[3] = p2[7];
    const bf16x8 pf0 = f0.v, pf1 = f1.v;
#pragma unroll
    for (int c = 0; c < 4; c++) {
      Oacc[c] = __builtin_amdgcn_mfma_f32_32x32x16_bf16(Vc[2 * c],     pf0, Oacc[c], 0, 0, 0);
      Oacc[c] = __builtin_amdgcn_mfma_f32_32x32x16_bf16(Vc[2 * c + 1], pf1, Oacc[c], 0, 0, 0);
    }
  };

  // ---- pipelined main loop, 1 barrier/tile, staggered tile order ----
  stage(t0, 0);
  __syncthreads();                 // tile t0 landed
  stage((t0 + 1) & 63, 1);
  body(0, t0);
#pragma unroll 1
  for (int lt = 1; lt < 64; ++lt) {
    __syncthreads();               // drains stage issued one body ago
    if (lt < 63) stage((lt + 1 + t0) & 63, (lt + 1) & 1);
    body(lt & 1, (lt + t0) & 63);
  }

  // ---- epilogue: publish l, kh-merge via ostage (ch rows), writeout ----
  float lfull = l_lane + __shfl_xor(l_lane, 32);
  if (lane < 32) sm.redu[w][l32] = lfull;
  __syncthreads();                 // kbuf reads done; redu published
  const int hb = lane >> 5;
  if (kh == 0) {
#pragma unroll
    for (int c = 0; c < 4; c++) {
#pragma unroll
      for (int r = 0; r < 16; r++) {
        int ch = (chh * 4 + c) * 32 + (r & 3) + 8 * (r >> 2) + 4 * hb;
        sm.u.ostage[ch][l32] = Oacc[c][r];
      }
    }
  }
  if (tid < 32) sm.rinv[tid] = 1.0f / (sm.redu[0][tid] + sm.redu[2][tid]);
  __syncthreads();
  if (kh == 1) {
#pragma unroll
    for (int c = 0; c < 4; c++) {
#pragma unroll
      for (int r = 0; r < 16; r++) {
        int ch = (chh * 4 + c) * 32 + (r & 3) + 8 * (r >> 2) + 4 * hb;
        sm.u.ostage[ch][l32] += Oacc[c][r];
      }
    }
  }
  __syncthreads();

  const float gmm = gammap[0];
  const int pix = tid & 31;
  const float ri = sm.rinv[pix];
#pragma unroll
  for (int j = 0; j < 32; ++j) {
    int ch = (tid >> 5) * 32 + j;
    size_t g = ((size_t)(b * 256 + ch)) * 4096 + n0 + pix;
    out[g] = gmm * sm.u.ostage[ch][pix] * ri + x_main[g];
  }
}

// ---------------------------------------------------------------------------
extern "C" void kernel_launch(void* const* d_in, const int* in_sizes, int n_in,
                              void* d_out, int out_size, void* d_ws, size_t ws_size,
                              hipStream_t stream) {
  (void)in_sizes; (void)n_in; (void)out_size; (void)ws_size;
  const float* x  = (const float*)d_in[0];
  const float* z  = (const float*)d_in[1];
  const float* Wq = (const float*)d_in[2];
  const float* bq = (const float*)d_in[3];
  const float* Wk = (const float*)d_in[4];
  const float* bk = (const float*)d_in[5];
  const float* Wv = (const float*)d_in[6];
  const float* bv = (const float*)d_in[7];
  const float* gm = (const float*)d_in[8];
  float* out = (float*)d_out;

  char* ws = (char*)d_ws;
  const size_t MB = 1024 * 1024;
  __hip_bfloat16* qp  = (__hip_bfloat16*)(ws);             // 4 MiB
  __hip_bfloat16* kp  = (__hip_bfloat16*)(ws + 4 * MB);    // 4 MiB
  __hip_bfloat16* vp  = (__hip_bfloat16*)(ws + 8 * MB);    // 8 MiB
  __hip_bfloat16* xfp = (__hip_bfloat16*)(ws + 16 * MB);   // 8 MiB
  __hip_bfloat16* zfp = (__hip_bfloat16*)(ws + 24 * MB);   // 8 MiB
  __hip_bfloat16* wfp = (__hip_bfloat16*)(ws + 32 * MB);   // 256 KiB

  prep_kernel<<<516, 256, 0, stream>>>(x, z, Wq, Wk, Wv, xfp, zfp, wfp);
  proj_mfma  <<<512, 256, 0, stream>>>(xfp, zfp, wfp, bq, bk, bv, qp, kp, vp);
  attn_kernel<<<512, 256, 0, stream>>>(qp, kp, vp, x, gm, out);
}